// Round 1
// baseline (1705.892 us; speedup 1.0000x reference)
//
#include <hip/hip_runtime.h>

#define T_TOK 2048
#define H_DIM 2048
#define F_DIM 7168
#define E_NUM 8
#define MAX_SLOTS 5120   // 4096 used slots + per-expert pad to 128
#define BM 128
#define BN 128
#define BK 64

typedef __attribute__((ext_vector_type(8))) _Float16 f16x8;
typedef __attribute__((ext_vector_type(4))) _Float16 f16x4;
typedef __attribute__((ext_vector_type(4))) float    f32x4;

// ---------------- small kernels ----------------

// convert hidden_states fp32 -> fp16 (coalesced, 4 elems/thread)
__global__ __launch_bounds__(256) void cvtx_kernel(const float* __restrict__ x,
                                                   _Float16* __restrict__ xb) {
    size_t i = ((size_t)blockIdx.x * 256 + threadIdx.x) * 4;
    float4 v = *(const float4*)(x + i);
    f16x4 h;
    h[0] = (_Float16)v.x; h[1] = (_Float16)v.y;
    h[2] = (_Float16)v.z; h[3] = (_Float16)v.w;
    *(f16x4*)(xb + i) = h;
}

// router: one wave per token; exact fp32 logits, softmax top-2, counts
__global__ __launch_bounds__(256) void router_kernel(
    const float* __restrict__ x, const float* __restrict__ wg,
    float* __restrict__ logits_out, int* __restrict__ tk_e,
    float* __restrict__ tk_w, int* __restrict__ meta) {
    int wave = threadIdx.x >> 6;
    int lane = threadIdx.x & 63;
    int t = blockIdx.x * 4 + wave;
    const float* xr = x + (size_t)t * H_DIM;

    float xv[32];
#pragma unroll
    for (int i = 0; i < 8; i++) {
        float4 v = *(const float4*)(xr + i * 256 + lane * 4);
        xv[i*4+0] = v.x; xv[i*4+1] = v.y; xv[i*4+2] = v.z; xv[i*4+3] = v.w;
    }
    float lg[E_NUM];
#pragma unroll
    for (int e = 0; e < E_NUM; e++) {
        const float* wr = wg + (size_t)e * H_DIM;
        float acc = 0.f;
#pragma unroll
        for (int i = 0; i < 8; i++) {
            float4 v = *(const float4*)(wr + i * 256 + lane * 4);
            acc += xv[i*4+0]*v.x + xv[i*4+1]*v.y + xv[i*4+2]*v.z + xv[i*4+3]*v.w;
        }
#pragma unroll
        for (int s = 32; s > 0; s >>= 1) acc += __shfl_xor(acc, s, 64);
        lg[e] = acc;
    }
    if (lane == 0) {
        // top-2 on logits (== top-2 on softmax probs), ties -> lower index
        float b0 = -3e38f, b1 = -3e38f; int i0 = 0, i1 = 0;
#pragma unroll
        for (int e = 0; e < E_NUM; e++) {
            float le = lg[e];
            if (le > b0)      { b1 = b0; i1 = i0; b0 = le; i0 = e; }
            else if (le > b1) { b1 = le; i1 = e; }
        }
        // renormalized weights: w0 = p0/(p0+p1) = 1/(1+exp(l1-l0))
        float w0 = 1.f / (1.f + __expf(b1 - b0));
        float w1v = 1.f - w0;
#pragma unroll
        for (int e = 0; e < E_NUM; e++) logits_out[(size_t)t * E_NUM + e] = lg[e];
        tk_e[t*2+0] = i0; tk_w[t*2+0] = w0;
        tk_e[t*2+1] = i1; tk_w[t*2+1] = w1v;
        atomicAdd(&meta[i0], 1);
        atomicAdd(&meta[i1], 1);
    }
}

// meta layout: [0..7]=cnt, [8..15]=cnt_pad, [16..23]=base, [24..31]=fill
__global__ void scan_kernel(int* __restrict__ meta, int* __restrict__ slot_tok,
                            float* __restrict__ slot_w) {
    int lane = threadIdx.x;  // 64 threads
    int cnts[E_NUM], pads[E_NUM], bases[E_NUM];
    int run = 0;
#pragma unroll
    for (int e = 0; e < E_NUM; e++) {
        cnts[e] = meta[e];
        pads[e] = (cnts[e] + BM - 1) & ~(BM - 1);
        bases[e] = run;
        run += pads[e];
    }
    if (lane < E_NUM) { meta[8 + lane] = pads[lane]; meta[16 + lane] = bases[lane]; }
    // fill padding slots: token 0, weight 0 (harmless compute, zero contribution)
    for (int e = 0; e < E_NUM; e++)
        for (int i = cnts[e] + lane; i < pads[e]; i += 64) {
            slot_tok[bases[e] + i] = 0;
            slot_w[bases[e] + i] = 0.f;
        }
}

__global__ __launch_bounds__(256) void assign_kernel(
    const int* __restrict__ tk_e, const float* __restrict__ tk_w,
    int* __restrict__ meta, int* __restrict__ slot_tok, float* __restrict__ slot_w) {
    int t = blockIdx.x * 256 + threadIdx.x;
    if (t >= T_TOK) return;
#pragma unroll
    for (int k = 0; k < 2; k++) {
        int e = tk_e[t*2+k];
        int pos = atomicAdd(&meta[24 + e], 1);
        int s = meta[16 + e] + pos;
        slot_tok[s] = t;
        slot_w[s] = tk_w[t*2+k];
    }
}

// ---------------- grouped GEMMs ----------------
// Stage 1: h[slot,f] = silu(x.w1[e,f,:]) * (x.w3[e,f,:]), fp16 out.
__global__ __launch_bounds__(256) void ffn1_kernel(
    const _Float16* __restrict__ xb, const float* __restrict__ w1,
    const float* __restrict__ w3, const int* __restrict__ slot_tok,
    const int* __restrict__ meta, _Float16* __restrict__ hbuf) {
    int e = blockIdx.z;
    int cntpad = meta[8 + e];
    int mb = blockIdx.y;
    if (mb * BM >= cntpad) return;
    int base = meta[16 + e];
    int nb = blockIdx.x;

    __shared__ _Float16 sA[BM][BK + 8];
    __shared__ _Float16 sB1[BN][BK + 8];
    __shared__ _Float16 sB3[BN][BK + 8];

    int tid = threadIdx.x;
    int lane = tid & 63;
    int wave = tid >> 6;
    int wm = wave >> 1, wn = wave & 1;         // 2x2 wave grid, 64x64 each
    int lr = lane & 15, lk = (lane >> 4) * 8;

    int r2 = tid >> 1;                          // staging row 0..127
    int c2 = (tid & 1) * 32;                    // staging col chunk

    int slot0 = base + mb * BM;
    int tokA = slot_tok[slot0 + r2];
    const _Float16* aSrc = xb + (size_t)tokA * H_DIM + c2;
    const float* b1Src = w1 + ((size_t)e * F_DIM + (size_t)nb * BN + r2) * H_DIM + c2;
    const float* b3Src = w3 + ((size_t)e * F_DIM + (size_t)nb * BN + r2) * H_DIM + c2;

    f32x4 zero = {0.f, 0.f, 0.f, 0.f};
    f32x4 acc1[4][4], acc3[4][4];
#pragma unroll
    for (int m = 0; m < 4; m++)
#pragma unroll
        for (int n = 0; n < 4; n++) { acc1[m][n] = zero; acc3[m][n] = zero; }

    for (int k0 = 0; k0 < H_DIM; k0 += BK) {
        __syncthreads();
        // stage A (fp16 copy, 4x16B per thread)
        {
            const _Float16* s = aSrc + k0;
#pragma unroll
            for (int q = 0; q < 4; q++) {
                uint4 v = *(const uint4*)(const void*)(s + q * 8);
                *(uint4*)(void*)&sA[r2][c2 + q * 8] = v;
            }
        }
        // stage B1/B3 (fp32 load -> fp16 convert -> 16B LDS writes)
        {
            const float* s1 = b1Src + k0;
            const float* s3 = b3Src + k0;
#pragma unroll
            for (int q = 0; q < 4; q++) {
                float4 fa = *(const float4*)(s1 + q * 8);
                float4 fb = *(const float4*)(s1 + q * 8 + 4);
                f16x8 p1;
                p1[0]=(_Float16)fa.x; p1[1]=(_Float16)fa.y; p1[2]=(_Float16)fa.z; p1[3]=(_Float16)fa.w;
                p1[4]=(_Float16)fb.x; p1[5]=(_Float16)fb.y; p1[6]=(_Float16)fb.z; p1[7]=(_Float16)fb.w;
                *(f16x8*)(void*)&sB1[r2][c2 + q * 8] = p1;
                float4 ga = *(const float4*)(s3 + q * 8);
                float4 gb = *(const float4*)(s3 + q * 8 + 4);
                f16x8 p3;
                p3[0]=(_Float16)ga.x; p3[1]=(_Float16)ga.y; p3[2]=(_Float16)ga.z; p3[3]=(_Float16)ga.w;
                p3[4]=(_Float16)gb.x; p3[5]=(_Float16)gb.y; p3[6]=(_Float16)gb.z; p3[7]=(_Float16)gb.w;
                *(f16x8*)(void*)&sB3[r2][c2 + q * 8] = p3;
            }
        }
        __syncthreads();
#pragma unroll
        for (int ks = 0; ks < BK; ks += 32) {
            f16x8 af[4], bf1[4], bf3[4];
#pragma unroll
            for (int m = 0; m < 4; m++)
                af[m] = *(const f16x8*)(const void*)&sA[wm*64 + m*16 + lr][ks + lk];
#pragma unroll
            for (int n = 0; n < 4; n++) {
                bf1[n] = *(const f16x8*)(const void*)&sB1[wn*64 + n*16 + lr][ks + lk];
                bf3[n] = *(const f16x8*)(const void*)&sB3[wn*64 + n*16 + lr][ks + lk];
            }
#pragma unroll
            for (int m = 0; m < 4; m++)
#pragma unroll
                for (int n = 0; n < 4; n++) {
                    acc1[m][n] = __builtin_amdgcn_mfma_f32_16x16x32_f16(af[m], bf1[n], acc1[m][n], 0, 0, 0);
                    acc3[m][n] = __builtin_amdgcn_mfma_f32_16x16x32_f16(af[m], bf3[n], acc3[m][n], 0, 0, 0);
                }
        }
    }
    // epilogue: silu(a1)*a3 -> fp16 hbuf.  C/D layout: col=lane&15, row=(lane>>4)*4+reg
    int row0 = mb * BM + wm * 64;
    int col0 = (size_t)0 + nb * BN + wn * 64;
#pragma unroll
    for (int m = 0; m < 4; m++) {
#pragma unroll
        for (int n = 0; n < 4; n++) {
            int col = col0 + n * 16 + lr;
            f32x4 v1 = acc1[m][n], v3 = acc3[m][n];
#pragma unroll
            for (int j = 0; j < 4; j++) {
                int slot = base + row0 + m * 16 + (lane >> 4) * 4 + j;
                float a1 = v1[j], a3 = v3[j];
                float hv = a1 * a3 / (1.f + __expf(-a1));
                hbuf[(size_t)slot * F_DIM + col] = (_Float16)hv;
            }
        }
    }
}

// Stage 2: out[tok,:] += w_slot * (h[slot,:] @ w2[e].T)   (2 atomic adds/elem total)
__global__ __launch_bounds__(256) void ffn2_kernel(
    const _Float16* __restrict__ hbuf, const float* __restrict__ w2,
    const int* __restrict__ slot_tok, const float* __restrict__ slot_w,
    const int* __restrict__ meta, float* __restrict__ out) {
    int e = blockIdx.z;
    int cntpad = meta[8 + e];
    int mb = blockIdx.y;
    if (mb * BM >= cntpad) return;
    int base = meta[16 + e];
    int nb = blockIdx.x;

    __shared__ _Float16 sA[BM][BK + 8];
    __shared__ _Float16 sB[BN][BK + 8];

    int tid = threadIdx.x;
    int lane = tid & 63;
    int wave = tid >> 6;
    int wm = wave >> 1, wn = wave & 1;
    int lr = lane & 15, lk = (lane >> 4) * 8;

    int r2 = tid >> 1;
    int c2 = (tid & 1) * 32;

    int slot0 = base + mb * BM;
    const _Float16* aSrc = hbuf + (size_t)(slot0 + r2) * F_DIM + c2;
    const float* bSrc = w2 + ((size_t)e * H_DIM + (size_t)nb * BN + r2) * F_DIM + c2;

    f32x4 zero = {0.f, 0.f, 0.f, 0.f};
    f32x4 acc[4][4];
#pragma unroll
    for (int m = 0; m < 4; m++)
#pragma unroll
        for (int n = 0; n < 4; n++) acc[m][n] = zero;

    for (int k0 = 0; k0 < F_DIM; k0 += BK) {
        __syncthreads();
        {
            const _Float16* s = aSrc + k0;
#pragma unroll
            for (int q = 0; q < 4; q++) {
                uint4 v = *(const uint4*)(const void*)(s + q * 8);
                *(uint4*)(void*)&sA[r2][c2 + q * 8] = v;
            }
        }
        {
            const float* s1 = bSrc + k0;
#pragma unroll
            for (int q = 0; q < 4; q++) {
                float4 fa = *(const float4*)(s1 + q * 8);
                float4 fb = *(const float4*)(s1 + q * 8 + 4);
                f16x8 p1;
                p1[0]=(_Float16)fa.x; p1[1]=(_Float16)fa.y; p1[2]=(_Float16)fa.z; p1[3]=(_Float16)fa.w;
                p1[4]=(_Float16)fb.x; p1[5]=(_Float16)fb.y; p1[6]=(_Float16)fb.z; p1[7]=(_Float16)fb.w;
                *(f16x8*)(void*)&sB[r2][c2 + q * 8] = p1;
            }
        }
        __syncthreads();
#pragma unroll
        for (int ks = 0; ks < BK; ks += 32) {
            f16x8 af[4], bf[4];
#pragma unroll
            for (int m = 0; m < 4; m++)
                af[m] = *(const f16x8*)(const void*)&sA[wm*64 + m*16 + lr][ks + lk];
#pragma unroll
            for (int n = 0; n < 4; n++)
                bf[n] = *(const f16x8*)(const void*)&sB[wn*64 + n*16 + lr][ks + lk];
#pragma unroll
            for (int m = 0; m < 4; m++)
#pragma unroll
                for (int n = 0; n < 4; n++)
                    acc[m][n] = __builtin_amdgcn_mfma_f32_16x16x32_f16(af[m], bf[n], acc[m][n], 0, 0, 0);
        }
    }
    int row0 = mb * BM + wm * 64;
    int col0 = nb * BN + wn * 64;
#pragma unroll
    for (int m = 0; m < 4; m++) {
        int rb = row0 + m * 16 + (lane >> 4) * 4;
        int toks[4]; float wts[4];
#pragma unroll
        for (int j = 0; j < 4; j++) {
            int s = base + rb + j;
            toks[j] = slot_tok[s];
            wts[j]  = slot_w[s];
        }
#pragma unroll
        for (int n = 0; n < 4; n++) {
            int col = col0 + n * 16 + lr;
            f32x4 v = acc[m][n];
#pragma unroll
            for (int j = 0; j < 4; j++)
                atomicAdd(&out[(size_t)toks[j] * H_DIM + col], v[j] * wts[j]);
        }
    }
}

// ---------------- launcher ----------------
extern "C" void kernel_launch(void* const* d_in, const int* in_sizes, int n_in,
                              void* d_out, int out_size, void* d_ws, size_t ws_size,
                              hipStream_t stream) {
    const float* x  = (const float*)d_in[0];
    const float* wg = (const float*)d_in[1];
    const float* w1 = (const float*)d_in[2];
    const float* w3 = (const float*)d_in[3];
    const float* w2 = (const float*)d_in[4];
    float* out = (float*)d_out;
    float* logits = out + (size_t)T_TOK * H_DIM;   // output 1 follows output 0

    // workspace layout
    char* ws = (char*)d_ws;
    _Float16* hbuf = (_Float16*)ws;                                   // MAX_SLOTS*F*2 = 73.4MB
    _Float16* xb   = (_Float16*)(ws + (size_t)MAX_SLOTS * F_DIM * 2); // T*H*2 = 8.4MB
    char* p = ws + (size_t)MAX_SLOTS * F_DIM * 2 + (size_t)T_TOK * H_DIM * 2;
    int*   slot_tok = (int*)p;   p += MAX_SLOTS * 4;
    float* slot_w   = (float*)p; p += MAX_SLOTS * 4;
    int*   tk_e     = (int*)p;   p += T_TOK * 2 * 4;
    float* tk_w     = (float*)p; p += T_TOK * 2 * 4;
    int*   meta     = (int*)p;   // 32 ints

    hipMemsetAsync(d_out, 0, (size_t)out_size * sizeof(float), stream);
    hipMemsetAsync(meta, 0, 32 * sizeof(int), stream);

    cvtx_kernel<<<dim3((T_TOK * H_DIM) / (256 * 4)), 256, 0, stream>>>(x, xb);
    router_kernel<<<dim3(T_TOK / 4), 256, 0, stream>>>(x, wg, logits, tk_e, tk_w, meta);
    scan_kernel<<<dim3(1), 64, 0, stream>>>(meta, slot_tok, slot_w);
    assign_kernel<<<dim3(T_TOK / 256), 256, 0, stream>>>(tk_e, tk_w, meta, slot_tok, slot_w);
    ffn1_kernel<<<dim3(F_DIM / BN, 16, E_NUM), 256, 0, stream>>>(xb, w1, w3, slot_tok, meta, hbuf);
    ffn2_kernel<<<dim3(H_DIM / BN, 16, E_NUM), 256, 0, stream>>>(hbuf, w2, slot_tok, slot_w, meta, out);
}

// Round 2
// 1146.663 us; speedup vs baseline: 1.4877x; 1.4877x over previous
//
#include <hip/hip_runtime.h>

#define T_TOK 2048
#define H_DIM 2048
#define F_DIM 7168
#define E_NUM 8
#define MAX_SLOTS 5120   // 4096 used slots + per-expert pad to 128
#define BM 128
#define BN 128
#define BK 64

typedef __attribute__((ext_vector_type(8))) _Float16 f16x8;
typedef __attribute__((ext_vector_type(4))) _Float16 f16x4;
typedef __attribute__((ext_vector_type(4))) float    f32x4;

// async global->LDS, 16B per lane; LDS dest is wave-uniform base + lane*16
#define GLL(g, l) __builtin_amdgcn_global_load_lds(                          \
    (const __attribute__((address_space(1))) void*)(g),                      \
    (__attribute__((address_space(3))) void*)(l), 16, 0, 0)

// ---------------- small kernels ----------------

// fp32 -> fp16 bulk convert, 8 elems/thread, coalesced
__global__ __launch_bounds__(256) void cvtw_kernel(const float* __restrict__ src,
                                                   _Float16* __restrict__ dst) {
    size_t i = ((size_t)blockIdx.x * 256 + threadIdx.x) * 8;
    float4 a = *(const float4*)(src + i);
    float4 b = *(const float4*)(src + i + 4);
    f16x8 h;
    h[0]=(_Float16)a.x; h[1]=(_Float16)a.y; h[2]=(_Float16)a.z; h[3]=(_Float16)a.w;
    h[4]=(_Float16)b.x; h[5]=(_Float16)b.y; h[6]=(_Float16)b.z; h[7]=(_Float16)b.w;
    *(f16x8*)(dst + i) = h;
}

// router: one wave per token; exact fp32 logits, softmax top-2, counts
__global__ __launch_bounds__(256) void router_kernel(
    const float* __restrict__ x, const float* __restrict__ wg,
    float* __restrict__ logits_out, int* __restrict__ tk_e,
    float* __restrict__ tk_w, int* __restrict__ meta) {
    int wave = threadIdx.x >> 6;
    int lane = threadIdx.x & 63;
    int t = blockIdx.x * 4 + wave;
    const float* xr = x + (size_t)t * H_DIM;

    float xv[32];
#pragma unroll
    for (int i = 0; i < 8; i++) {
        float4 v = *(const float4*)(xr + i * 256 + lane * 4);
        xv[i*4+0] = v.x; xv[i*4+1] = v.y; xv[i*4+2] = v.z; xv[i*4+3] = v.w;
    }
    float lg[E_NUM];
#pragma unroll
    for (int e = 0; e < E_NUM; e++) {
        const float* wr = wg + (size_t)e * H_DIM;
        float acc = 0.f;
#pragma unroll
        for (int i = 0; i < 8; i++) {
            float4 v = *(const float4*)(wr + i * 256 + lane * 4);
            acc += xv[i*4+0]*v.x + xv[i*4+1]*v.y + xv[i*4+2]*v.z + xv[i*4+3]*v.w;
        }
#pragma unroll
        for (int s = 32; s > 0; s >>= 1) acc += __shfl_xor(acc, s, 64);
        lg[e] = acc;
    }
    if (lane == 0) {
        float b0 = -3e38f, b1 = -3e38f; int i0 = 0, i1 = 0;
#pragma unroll
        for (int e = 0; e < E_NUM; e++) {
            float le = lg[e];
            if (le > b0)      { b1 = b0; i1 = i0; b0 = le; i0 = e; }
            else if (le > b1) { b1 = le; i1 = e; }
        }
        float w0 = 1.f / (1.f + __expf(b1 - b0));
        float w1v = 1.f - w0;
#pragma unroll
        for (int e = 0; e < E_NUM; e++) logits_out[(size_t)t * E_NUM + e] = lg[e];
        tk_e[t*2+0] = i0; tk_w[t*2+0] = w0;
        tk_e[t*2+1] = i1; tk_w[t*2+1] = w1v;
        atomicAdd(&meta[i0], 1);
        atomicAdd(&meta[i1], 1);
    }
}

// meta layout: [0..7]=cnt, [8..15]=cnt_pad, [16..23]=base, [24..31]=fill
__global__ void scan_kernel(int* __restrict__ meta, int* __restrict__ slot_tok,
                            float* __restrict__ slot_w) {
    int lane = threadIdx.x;  // 64 threads
    int cnts[E_NUM], pads[E_NUM], bases[E_NUM];
    int run = 0;
#pragma unroll
    for (int e = 0; e < E_NUM; e++) {
        cnts[e] = meta[e];
        pads[e] = (cnts[e] + BM - 1) & ~(BM - 1);
        bases[e] = run;
        run += pads[e];
    }
    if (lane < E_NUM) { meta[8 + lane] = pads[lane]; meta[16 + lane] = bases[lane]; }
    for (int e = 0; e < E_NUM; e++)
        for (int i = cnts[e] + lane; i < pads[e]; i += 64) {
            slot_tok[bases[e] + i] = 0;
            slot_w[bases[e] + i] = 0.f;
        }
}

__global__ __launch_bounds__(256) void assign_kernel(
    const int* __restrict__ tk_e, const float* __restrict__ tk_w,
    int* __restrict__ meta, int* __restrict__ slot_tok, float* __restrict__ slot_w) {
    int t = blockIdx.x * 256 + threadIdx.x;
    if (t >= T_TOK) return;
#pragma unroll
    for (int k = 0; k < 2; k++) {
        int e = tk_e[t*2+k];
        int pos = atomicAdd(&meta[24 + e], 1);
        int s = meta[16 + e] + pos;
        slot_tok[s] = t;
        slot_w[s] = tk_w[t*2+k];
    }
}

// ---------------- grouped GEMMs (fp16, global_load_lds, m97 structure) ----------------

// Stage 1: h[slot,f] = silu(x.w1[e,f,:]) * (x.w3[e,f,:]), fp16 out.
__global__ __launch_bounds__(256, 2) void ffn1_kernel(
    const _Float16* __restrict__ xb, const _Float16* __restrict__ w1h,
    const _Float16* __restrict__ w3h, const int* __restrict__ slot_tok,
    const int* __restrict__ meta, _Float16* __restrict__ hbuf) {
    int e = blockIdx.z;
    int cntpad = meta[8 + e];
    int mb = blockIdx.y;
    if (mb * BM >= cntpad) return;
    int base = meta[16 + e];
    int nb = blockIdx.x;

    __shared__ _Float16 sA[BM][BK];
    __shared__ _Float16 sB1[BN][BK];
    __shared__ _Float16 sB3[BN][BK];

    int tid = threadIdx.x;
    int lane = tid & 63;
    int wave = tid >> 6;
    int wm = wave >> 1, wn = wave & 1;        // 2x2 wave grid, 64x64 tiles
    int lr = lane & 15, lk = (lane >> 4) * 8;

    // staging: per wave 4 chunks of 8 rows; lane covers (row=chunk*8+lane/8, col=(lane&7)*8)
    int rsub = lane >> 3;
    int colc = (lane & 7) * 8;
    int slot0 = base + mb * BM;

    const _Float16* aG[4];
    const _Float16* b1G[4];
    const _Float16* b3G[4];
#pragma unroll
    for (int q = 0; q < 4; q++) {
        int row = wave * 32 + q * 8 + rsub;
        int tok = slot_tok[slot0 + row];
        aG[q] = xb + (size_t)tok * H_DIM + colc;
        size_t wrow = (size_t)e * F_DIM + (size_t)nb * BN + row;
        b1G[q] = w1h + wrow * H_DIM + colc;
        b3G[q] = w3h + wrow * H_DIM + colc;
    }

    f32x4 zero = {0.f, 0.f, 0.f, 0.f};
    f32x4 acc1[4][4], acc3[4][4];
#pragma unroll
    for (int m = 0; m < 4; m++)
#pragma unroll
        for (int n = 0; n < 4; n++) { acc1[m][n] = zero; acc3[m][n] = zero; }

    for (int k0 = 0; k0 < H_DIM; k0 += BK) {
        __syncthreads();
#pragma unroll
        for (int q = 0; q < 4; q++) {
            GLL(aG[q] + k0,  &sA[wave * 32 + q * 8][0]);
            GLL(b1G[q] + k0, &sB1[wave * 32 + q * 8][0]);
            GLL(b3G[q] + k0, &sB3[wave * 32 + q * 8][0]);
        }
        __syncthreads();   // drains vmcnt -> LDS ready
#pragma unroll
        for (int ks = 0; ks < BK; ks += 32) {
            f16x8 af[4], bf1[4], bf3[4];
#pragma unroll
            for (int m = 0; m < 4; m++)
                af[m] = *(const f16x8*)(const void*)&sA[wm*64 + m*16 + lr][ks + lk];
#pragma unroll
            for (int n = 0; n < 4; n++) {
                bf1[n] = *(const f16x8*)(const void*)&sB1[wn*64 + n*16 + lr][ks + lk];
                bf3[n] = *(const f16x8*)(const void*)&sB3[wn*64 + n*16 + lr][ks + lk];
            }
#pragma unroll
            for (int m = 0; m < 4; m++)
#pragma unroll
                for (int n = 0; n < 4; n++) {
                    acc1[m][n] = __builtin_amdgcn_mfma_f32_16x16x32_f16(af[m], bf1[n], acc1[m][n], 0, 0, 0);
                    acc3[m][n] = __builtin_amdgcn_mfma_f32_16x16x32_f16(af[m], bf3[n], acc3[m][n], 0, 0, 0);
                }
        }
    }
    // epilogue: silu(a1)*a3 -> fp16 hbuf.  C/D: col=lane&15, row=(lane>>4)*4+reg
    int row0 = mb * BM + wm * 64;
    int col0 = nb * BN + wn * 64;
#pragma unroll
    for (int m = 0; m < 4; m++) {
#pragma unroll
        for (int n = 0; n < 4; n++) {
            int col = col0 + n * 16 + lr;
            f32x4 v1 = acc1[m][n], v3 = acc3[m][n];
#pragma unroll
            for (int j = 0; j < 4; j++) {
                int slot = base + row0 + m * 16 + (lane >> 4) * 4 + j;
                float a1 = v1[j], a3 = v3[j];
                float hv = a1 * a3 / (1.f + __expf(-a1));
                hbuf[(size_t)slot * F_DIM + col] = (_Float16)hv;
            }
        }
    }
}

// Stage 2: out[tok,:] += w_slot * (h[slot,:] @ w2[e].T)
__global__ __launch_bounds__(256, 2) void ffn2_kernel(
    const _Float16* __restrict__ hbuf, const _Float16* __restrict__ w2h,
    const int* __restrict__ slot_tok, const float* __restrict__ slot_w,
    const int* __restrict__ meta, float* __restrict__ out) {
    int e = blockIdx.z;
    int cntpad = meta[8 + e];
    int mb = blockIdx.y;
    if (mb * BM >= cntpad) return;
    int base = meta[16 + e];
    int nb = blockIdx.x;

    __shared__ _Float16 sA[BM][BK];
    __shared__ _Float16 sB[BN][BK];

    int tid = threadIdx.x;
    int lane = tid & 63;
    int wave = tid >> 6;
    int wm = wave >> 1, wn = wave & 1;
    int lr = lane & 15, lk = (lane >> 4) * 8;

    int rsub = lane >> 3;
    int colc = (lane & 7) * 8;
    int slot0 = base + mb * BM;

    const _Float16* aG[4];
    const _Float16* bG[4];
#pragma unroll
    for (int q = 0; q < 4; q++) {
        int row = wave * 32 + q * 8 + rsub;
        aG[q] = hbuf + (size_t)(slot0 + row) * F_DIM + colc;
        bG[q] = w2h + ((size_t)e * H_DIM + (size_t)nb * BN + row) * F_DIM + colc;
    }

    f32x4 zero = {0.f, 0.f, 0.f, 0.f};
    f32x4 acc[4][4];
#pragma unroll
    for (int m = 0; m < 4; m++)
#pragma unroll
        for (int n = 0; n < 4; n++) acc[m][n] = zero;

    for (int k0 = 0; k0 < F_DIM; k0 += BK) {
        __syncthreads();
#pragma unroll
        for (int q = 0; q < 4; q++) {
            GLL(aG[q] + k0, &sA[wave * 32 + q * 8][0]);
            GLL(bG[q] + k0, &sB[wave * 32 + q * 8][0]);
        }
        __syncthreads();
#pragma unroll
        for (int ks = 0; ks < BK; ks += 32) {
            f16x8 af[4], bf[4];
#pragma unroll
            for (int m = 0; m < 4; m++)
                af[m] = *(const f16x8*)(const void*)&sA[wm*64 + m*16 + lr][ks + lk];
#pragma unroll
            for (int n = 0; n < 4; n++)
                bf[n] = *(const f16x8*)(const void*)&sB[wn*64 + n*16 + lr][ks + lk];
#pragma unroll
            for (int m = 0; m < 4; m++)
#pragma unroll
                for (int n = 0; n < 4; n++)
                    acc[m][n] = __builtin_amdgcn_mfma_f32_16x16x32_f16(af[m], bf[n], acc[m][n], 0, 0, 0);
        }
    }
    int row0 = mb * BM + wm * 64;
    int col0 = nb * BN + wn * 64;
#pragma unroll
    for (int m = 0; m < 4; m++) {
        int rb = row0 + m * 16 + (lane >> 4) * 4;
        int toks[4]; float wts[4];
#pragma unroll
        for (int j = 0; j < 4; j++) {
            int s = base + rb + j;
            toks[j] = slot_tok[s];
            wts[j]  = slot_w[s];
        }
#pragma unroll
        for (int n = 0; n < 4; n++) {
            int col = col0 + n * 16 + lr;
            f32x4 v = acc[m][n];
#pragma unroll
            for (int j = 0; j < 4; j++)
                atomicAdd(&out[(size_t)toks[j] * H_DIM + col], v[j] * wts[j]);
        }
    }
}

// ---------------- launcher ----------------
extern "C" void kernel_launch(void* const* d_in, const int* in_sizes, int n_in,
                              void* d_out, int out_size, void* d_ws, size_t ws_size,
                              hipStream_t stream) {
    const float* x  = (const float*)d_in[0];
    const float* wg = (const float*)d_in[1];
    const float* w1 = (const float*)d_in[2];
    const float* w3 = (const float*)d_in[3];
    const float* w2 = (const float*)d_in[4];
    float* out = (float*)d_out;
    float* logits = out + (size_t)T_TOK * H_DIM;   // output 1 follows output 0

    const size_t WELEM = (size_t)E_NUM * F_DIM * H_DIM;   // 58,720,256 per tensor

    // workspace layout
    char* ws = (char*)d_ws;
    _Float16* w1h  = (_Float16*)ws;                       // 112 MiB
    _Float16* w3h  = w1h + WELEM;                         // 112 MiB
    _Float16* w2h  = w3h + WELEM;                         // 112 MiB
    _Float16* hbuf = w2h + WELEM;                         // 70 MiB
    _Float16* xb   = hbuf + (size_t)MAX_SLOTS * F_DIM;    // 8 MiB
    char* p = (char*)(xb + (size_t)T_TOK * H_DIM);
    int*   slot_tok = (int*)p;   p += MAX_SLOTS * 4;
    float* slot_w   = (float*)p; p += MAX_SLOTS * 4;
    int*   tk_e     = (int*)p;   p += T_TOK * 2 * 4;
    float* tk_w     = (float*)p; p += T_TOK * 2 * 4;
    int*   meta     = (int*)p;   // 32 ints

    hipMemsetAsync(d_out, 0, (size_t)out_size * sizeof(float), stream);
    hipMemsetAsync(meta, 0, 32 * sizeof(int), stream);

    // weight conversions (memory-bound)
    cvtw_kernel<<<dim3(WELEM / (256 * 8)), 256, 0, stream>>>(w1, w1h);
    cvtw_kernel<<<dim3(WELEM / (256 * 8)), 256, 0, stream>>>(w3, w3h);
    cvtw_kernel<<<dim3(WELEM / (256 * 8)), 256, 0, stream>>>(w2, w2h);
    cvtw_kernel<<<dim3((size_t)T_TOK * H_DIM / (256 * 8)), 256, 0, stream>>>(x, xb);

    router_kernel<<<dim3(T_TOK / 4), 256, 0, stream>>>(x, wg, logits, tk_e, tk_w, meta);
    scan_kernel<<<dim3(1), 64, 0, stream>>>(meta, slot_tok, slot_w);
    assign_kernel<<<dim3(T_TOK / 256), 256, 0, stream>>>(tk_e, tk_w, meta, slot_tok, slot_w);

    ffn1_kernel<<<dim3(F_DIM / BN, 16, E_NUM), 256, 0, stream>>>(xb, w1h, w3h, slot_tok, meta, hbuf);
    ffn2_kernel<<<dim3(H_DIM / BN, 16, E_NUM), 256, 0, stream>>>(hbuf, w2h, slot_tok, slot_w, meta, out);
}